// Round 1
// baseline (580.726 us; speedup 1.0000x reference)
//
#include <hip/hip_runtime.h>
#include <hip/hip_bf16.h>
#include <cstdint>
#include <cstddef>

typedef __attribute__((ext_vector_type(4))) float f32x4;
typedef __attribute__((ext_vector_type(8))) __bf16 bf16x8;

constexpr int Bc = 4, Sc = 2048, Dc = 1024, Hc = 16, HDc = 64;
constexpr int Mrows = Bc * Sc;   // 8192
constexpr int Kdim = Dc;         // 1024
constexpr int Ndim = Dc;         // 1024

__device__ __forceinline__ void gload_lds16(const void* g, void* lds) {
  __builtin_amdgcn_global_load_lds(
      (const __attribute__((address_space(1))) void*)g,
      (__attribute__((address_space(3))) void*)lds, 16, 0, 0);
}

// ---------------- fp32 -> bf16 convert (vectorized) ----------------
__global__ void cvt_f32_to_bf16(const float* __restrict__ src,
                                __bf16* __restrict__ dst, int n4) {
  int i = blockIdx.x * blockDim.x + threadIdx.x;
  if (i >= n4) return;
  float4 f = ((const float4*)src)[i];
  union { __bf16 h[4]; uint2 u; } p;
  p.h[0] = (__bf16)f.x; p.h[1] = (__bf16)f.y;
  p.h[2] = (__bf16)f.z; p.h[3] = (__bf16)f.w;
  ((uint2*)dst)[i] = p.u;
}

// ---------------- GEMM: C[M,N] = A[M,K] * Bw[N,K]^T + bias ----------------
// OUT_MODE 0: bf16 out, per-head layout [B,H,S,HD], value scaled by `scale`
// OUT_MODE 1: fp32 out, row-major [M,N]
template<int OUT_MODE>
__global__ __launch_bounds__(256, 2)
void gemm_bt(const __bf16* __restrict__ A, const __bf16* __restrict__ Bw,
             const float* __restrict__ bias, void* __restrict__ outp,
             float scale)
{
  __shared__ __align__(16) __bf16 As[128 * 32];
  __shared__ __align__(16) __bf16 Bs[128 * 32];
  const int tid = threadIdx.x;
  const int wave = tid >> 6, lane = tid & 63;
  const int wr = wave >> 1, wc = wave & 1;
  const int r = lane & 15, hi = lane >> 4;
  const int m0 = blockIdx.y * 128, n0 = blockIdx.x * 128;

  f32x4 acc[4][4] = {};

  for (int k0 = 0; k0 < Kdim; k0 += 32) {
    // stage A,B tiles: 512 16B chunks each; LDS linear, global src pre-swizzled
    #pragma unroll
    for (int c = 0; c < 2; ++c) {
      int chunk = c * 256 + wave * 64 + lane;
      int row = chunk >> 2;
      int hc = (chunk & 3) ^ (row & 3);   // pre-swizzled source block
      gload_lds16(A  + (size_t)(m0 + row) * Kdim + k0 + hc * 8,
                  &As[(size_t)(c * 256 + wave * 64) * 8]);
      gload_lds16(Bw + (size_t)(n0 + row) * Kdim + k0 + hc * 8,
                  &Bs[(size_t)(c * 256 + wave * 64) * 8]);
    }
    __syncthreads();
    bf16x8 af[4], bfr[4];
    #pragma unroll
    for (int m = 0; m < 4; ++m) {
      int rowl = wr * 64 + m * 16 + r;
      af[m] = *(const bf16x8*)&As[rowl * 32 + ((hi ^ (rowl & 3)) * 8)];
    }
    #pragma unroll
    for (int n = 0; n < 4; ++n) {
      int rowl = wc * 64 + n * 16 + r;
      bfr[n] = *(const bf16x8*)&Bs[rowl * 32 + ((hi ^ (rowl & 3)) * 8)];
    }
    #pragma unroll
    for (int m = 0; m < 4; ++m)
      #pragma unroll
      for (int n = 0; n < 4; ++n)
        acc[m][n] = __builtin_amdgcn_mfma_f32_16x16x32_bf16(af[m], bfr[n], acc[m][n], 0, 0, 0);
    __syncthreads();
  }

  #pragma unroll
  for (int m = 0; m < 4; ++m)
    #pragma unroll
    for (int n = 0; n < 4; ++n)
      #pragma unroll
      for (int rg = 0; rg < 4; ++rg) {
        int row_g = m0 + wr * 64 + m * 16 + hi * 4 + rg;
        int col_g = n0 + wc * 64 + n * 16 + r;
        float v = (acc[m][n][rg] + bias[col_g]) * scale;
        if (OUT_MODE == 0) {
          int b = row_g >> 11, s = row_g & (Sc - 1);
          int h = col_g >> 6, d = col_g & 63;
          ((__bf16*)outp)[((((size_t)b * Hc + h) * Sc + s) << 6) + d] = (__bf16)v;
        } else {
          ((float*)outp)[(size_t)row_g * Dc + col_g] = v;
        }
      }
}

// ---------------- causal flash attention ----------------
// Qh/Kh/Vh: [B*H][S][64] bf16 (Q pre-scaled by 1/8). out: [B][S][D] bf16.
__global__ __launch_bounds__(256, 2)
void attn_causal(const __bf16* __restrict__ Qh, const __bf16* __restrict__ Kh,
                 const __bf16* __restrict__ Vh, __bf16* __restrict__ outp)
{
  __shared__ __align__(16) __bf16 Kt[64 * 64];       // [kv][hd], XOR swizzled
  __shared__ __align__(16) __bf16 Vt[64 * 64];       // [hd][kv], XOR swizzled
  __shared__ __align__(16) __bf16 Pl[4][64 * 64];    // per-wave P, swizzled

  const int tid = threadIdx.x;
  const int wave = tid >> 6, lane = tid & 63;
  const int r = lane & 15, hi = lane >> 4;
  const int qb = blockIdx.x * 256;
  const int bh = blockIdx.y;
  const size_t base = (size_t)bh * Sc * HDc;
  const __bf16* Q = Qh + base;
  const __bf16* K = Kh + base;
  const __bf16* V = Vh + base;
  const int q0 = qb + wave * 64;

  // Q fragments in registers (A operand: row=lane&15, k=8*hi+j)
  bf16x8 qf[4][2];
  #pragma unroll
  for (int m = 0; m < 4; ++m)
    #pragma unroll
    for (int kc = 0; kc < 2; ++kc)
      qf[m][kc] = *(const bf16x8*)&Q[(size_t)(q0 + m * 16 + r) * 64 + kc * 32 + hi * 8];

  f32x4 o_acc[4][4] = {};
  float mrow[4][4], lrow[4][4];
  #pragma unroll
  for (int m = 0; m < 4; ++m)
    #pragma unroll
    for (int rg = 0; rg < 4; ++rg) { mrow[m][rg] = -1e30f; lrow[m][rg] = 0.f; }

  const int nkv = qb / 64 + 4;
  for (int t = 0; t < nkv; ++t) {
    const int kv0 = t * 64;
    // stage K: LDS linear dest, pre-swizzled global source
    #pragma unroll
    for (int c = 0; c < 2; ++c) {
      int chunk = c * 256 + wave * 64 + lane;
      int kv = chunk >> 3;
      int hc = (chunk & 7) ^ (kv & 7);
      gload_lds16(K + (size_t)(kv0 + kv) * 64 + hc * 8,
                  &Kt[(size_t)(c * 256 + wave * 64) * 8]);
    }
    // stage V transposed (register path, packed b32 writes)
    {
      int p2 = tid >> 3;             // kv pair index 0..31
      int h8 = (tid & 7) * 8;        // hd start
      union { uint4 u; ushort s[8]; } va, vb;
      va.u = *(const uint4*)&V[(size_t)(kv0 + 2 * p2) * 64 + h8];
      vb.u = *(const uint4*)&V[(size_t)(kv0 + 2 * p2 + 1) * 64 + h8];
      #pragma unroll
      for (int j = 0; j < 8; ++j) {
        int hd = h8 + j;
        int byteoff = (hd * 128 + p2 * 4) ^ ((hd & 7) << 4);
        *(uint32_t*)((char*)Vt + byteoff) =
            (uint32_t)va.s[j] | ((uint32_t)vb.s[j] << 16);
      }
    }
    __syncthreads();

    if (kv0 <= q0) {
      const bool diag = (kv0 == q0);
      bf16x8 kf[4][2];
      #pragma unroll
      for (int n = 0; n < 4; ++n)
        #pragma unroll
        for (int kc = 0; kc < 2; ++kc) {
          int kvc = n * 16 + r;
          int byteoff = (kvc * 128 + kc * 64 + hi * 16) ^ ((kvc & 7) << 4);
          kf[n][kc] = *(const bf16x8*)((const char*)Kt + byteoff);
        }
      f32x4 zero = {0.f, 0.f, 0.f, 0.f};
      #pragma unroll
      for (int m = 0; m < 4; ++m) {
        f32x4 s[4];
        #pragma unroll
        for (int n = 0; n < 4; ++n) {
          s[n] = __builtin_amdgcn_mfma_f32_16x16x32_bf16(qf[m][0], kf[n][0], zero, 0, 0, 0);
          s[n] = __builtin_amdgcn_mfma_f32_16x16x32_bf16(qf[m][1], kf[n][1], s[n], 0, 0, 0);
        }
        if (diag) {
          #pragma unroll
          for (int n = 0; n < 4; ++n)
            #pragma unroll
            for (int rg = 0; rg < 4; ++rg)
              if (n * 16 + r > m * 16 + hi * 4 + rg) s[n][rg] = -1e30f;
        }
        #pragma unroll
        for (int rg = 0; rg < 4; ++rg) {
          float tmax = fmaxf(fmaxf(s[0][rg], s[1][rg]), fmaxf(s[2][rg], s[3][rg]));
          tmax = fmaxf(tmax, __shfl_xor(tmax, 1));
          tmax = fmaxf(tmax, __shfl_xor(tmax, 2));
          tmax = fmaxf(tmax, __shfl_xor(tmax, 4));
          tmax = fmaxf(tmax, __shfl_xor(tmax, 8));
          float mnew = fmaxf(mrow[m][rg], tmax);
          float sc = __expf(mrow[m][rg] - mnew);
          float rsum = 0.f;
          #pragma unroll
          for (int n = 0; n < 4; ++n) {
            float p = __expf(s[n][rg] - mnew);
            s[n][rg] = p;
            rsum += p;
          }
          rsum += __shfl_xor(rsum, 1);
          rsum += __shfl_xor(rsum, 2);
          rsum += __shfl_xor(rsum, 4);
          rsum += __shfl_xor(rsum, 8);
          lrow[m][rg] = lrow[m][rg] * sc + rsum;
          mrow[m][rg] = mnew;
          #pragma unroll
          for (int n = 0; n < 4; ++n) o_acc[m][n][rg] *= sc;
        }
        // P -> LDS (bf16, swizzled)
        #pragma unroll
        for (int n = 0; n < 4; ++n)
          #pragma unroll
          for (int rg = 0; rg < 4; ++rg) {
            int ql = m * 16 + hi * 4 + rg;
            int kvl = n * 16 + r;
            int byteoff = (ql * 128 + kvl * 2) ^ ((ql & 7) << 4);
            *(__bf16*)((char*)Pl[wave] + byteoff) = (__bf16)s[n][rg];
          }
      }
      asm volatile("s_waitcnt lgkmcnt(0)" ::: "memory");
      // PV
      bf16x8 vf[4][2];
      #pragma unroll
      for (int n = 0; n < 4; ++n)
        #pragma unroll
        for (int kc = 0; kc < 2; ++kc) {
          int hd = n * 16 + r;
          int byteoff = (hd * 128 + kc * 64 + hi * 16) ^ ((hd & 7) << 4);
          vf[n][kc] = *(const bf16x8*)((const char*)Vt + byteoff);
        }
      #pragma unroll
      for (int m = 0; m < 4; ++m) {
        bf16x8 pf[2];
        #pragma unroll
        for (int kc = 0; kc < 2; ++kc) {
          int ql = m * 16 + r;
          int byteoff = (ql * 128 + kc * 64 + hi * 16) ^ ((ql & 7) << 4);
          pf[kc] = *(const bf16x8*)((const char*)Pl[wave] + byteoff);
        }
        #pragma unroll
        for (int n = 0; n < 4; ++n) {
          o_acc[m][n] = __builtin_amdgcn_mfma_f32_16x16x32_bf16(pf[0], vf[n][0], o_acc[m][n], 0, 0, 0);
          o_acc[m][n] = __builtin_amdgcn_mfma_f32_16x16x32_bf16(pf[1], vf[n][1], o_acc[m][n], 0, 0, 0);
        }
      }
    }
    __syncthreads();
  }

  const int b = bh >> 4, h = bh & 15;
  #pragma unroll
  for (int m = 0; m < 4; ++m)
    #pragma unroll
    for (int rg = 0; rg < 4; ++rg) {
      int ql = m * 16 + hi * 4 + rg;
      float inv = 1.f / lrow[m][rg];
      #pragma unroll
      for (int n = 0; n < 4; ++n) {
        int col = h * 64 + n * 16 + r;
        outp[((size_t)b * Sc + qb + wave * 64 + ql) * Dc + col] =
            (__bf16)(o_acc[m][n][rg] * inv);
      }
    }
}

// ---------------- launch ----------------
extern "C" void kernel_launch(void* const* d_in, const int* in_sizes, int n_in,
                              void* d_out, int out_size, void* d_ws, size_t ws_size,
                              hipStream_t stream) {
  const float* q  = (const float*)d_in[0];
  const float* k  = (const float*)d_in[1];
  const float* v  = (const float*)d_in[2];
  const float* Wq = (const float*)d_in[4];
  const float* bq = (const float*)d_in[5];
  const float* Wk = (const float*)d_in[6];
  const float* bk = (const float*)d_in[7];
  const float* Wv = (const float*)d_in[8];
  const float* bv = (const float*)d_in[9];
  const float* Wo = (const float*)d_in[10];
  const float* bo = (const float*)d_in[11];

  char* ws = (char*)d_ws;
  constexpr size_t MB = 1u << 20;
  __bf16* Wqb = (__bf16*)(ws + 0 * MB);
  __bf16* Wkb = (__bf16*)(ws + 2 * MB);
  __bf16* Wvb = (__bf16*)(ws + 4 * MB);
  __bf16* Wob = (__bf16*)(ws + 6 * MB);
  __bf16* Xbf = (__bf16*)(ws + 8 * MB);    // 16 MB: X (reused), then attn out
  __bf16* QhB = (__bf16*)(ws + 24 * MB);
  __bf16* KhB = (__bf16*)(ws + 40 * MB);
  __bf16* VhB = (__bf16*)(ws + 56 * MB);   // total 72 MB

  const int nW4 = (Dc * Dc) / 4;           // 262144
  const int nX4 = (Mrows * Dc) / 4;        // 2097152
  cvt_f32_to_bf16<<<(nW4 + 255) / 256, 256, 0, stream>>>(Wq, Wqb, nW4);
  cvt_f32_to_bf16<<<(nW4 + 255) / 256, 256, 0, stream>>>(Wk, Wkb, nW4);
  cvt_f32_to_bf16<<<(nW4 + 255) / 256, 256, 0, stream>>>(Wv, Wvb, nW4);
  cvt_f32_to_bf16<<<(nW4 + 255) / 256, 256, 0, stream>>>(Wo, Wob, nW4);

  dim3 gg(Ndim / 128, Mrows / 128);  // (8, 64)
  cvt_f32_to_bf16<<<(nX4 + 255) / 256, 256, 0, stream>>>(q, Xbf, nX4);
  gemm_bt<0><<<gg, 256, 0, stream>>>(Xbf, Wqb, bq, QhB, 0.125f);
  cvt_f32_to_bf16<<<(nX4 + 255) / 256, 256, 0, stream>>>(k, Xbf, nX4);
  gemm_bt<0><<<gg, 256, 0, stream>>>(Xbf, Wkb, bk, KhB, 1.0f);
  cvt_f32_to_bf16<<<(nX4 + 255) / 256, 256, 0, stream>>>(v, Xbf, nX4);
  gemm_bt<0><<<gg, 256, 0, stream>>>(Xbf, Wvb, bv, VhB, 1.0f);

  attn_causal<<<dim3(Sc / 256, Bc * Hc), 256, 0, stream>>>(QhB, KhB, VhB, Xbf);

  gemm_bt<1><<<gg, 256, 0, stream>>>(Xbf, Wob, bo, d_out, 1.0f);
}

// Round 3
// 285.360 us; speedup vs baseline: 2.0351x; 2.0351x over previous
//
#include <hip/hip_runtime.h>
#include <hip/hip_bf16.h>
#include <cstdint>
#include <cstddef>

typedef __attribute__((ext_vector_type(4))) float f32x4;
typedef __attribute__((ext_vector_type(8))) __bf16 bf16x8;

constexpr int Bc = 4, Sc = 2048, Dc = 1024, Hc = 16, HDc = 64;
constexpr int Mrows = Bc * Sc;   // 8192
constexpr int Kdim = Dc;         // 1024
constexpr int Ndim = Dc;         // 1024

__device__ __forceinline__ void gload_lds16(const void* g, void* lds) {
  __builtin_amdgcn_global_load_lds(
      (const __attribute__((address_space(1))) void*)g,
      (__attribute__((address_space(3))) void*)lds, 16, 0, 0);
}

// ---------------- fp32 -> bf16 convert (vectorized) ----------------
__global__ void cvt_f32_to_bf16(const float* __restrict__ src,
                                __bf16* __restrict__ dst, int n4) {
  int i = blockIdx.x * blockDim.x + threadIdx.x;
  if (i >= n4) return;
  float4 f = ((const float4*)src)[i];
  union { __bf16 h[4]; uint2 u; } p;
  p.h[0] = (__bf16)f.x; p.h[1] = (__bf16)f.y;
  p.h[2] = (__bf16)f.z; p.h[3] = (__bf16)f.w;
  ((uint2*)dst)[i] = p.u;
}

// ---------------- GEMM: C[M,N] = A[M,K] * Bw[N,K]^T + bias ----------------
// OUT_MODE 0: bf16 out, per-head layout [B,H,S,HD], value scaled by `scale`
// OUT_MODE 1: fp32 out, row-major [M,N]
// OUT_MODE 2: bf16 out, transposed per-head layout [B,H,HD,S] (for V^T)
template<int OUT_MODE>
__global__ __launch_bounds__(256, 2)
void gemm_bt(const __bf16* __restrict__ A, const __bf16* __restrict__ Bw,
             const float* __restrict__ bias, void* __restrict__ outp,
             float scale)
{
  __shared__ __align__(16) __bf16 As[128 * 32];
  __shared__ __align__(16) __bf16 Bs[128 * 32];
  const int tid = threadIdx.x;
  const int wave = tid >> 6, lane = tid & 63;
  const int wr = wave >> 1, wc = wave & 1;
  const int r = lane & 15, hi = lane >> 4;
  const int m0 = blockIdx.y * 128, n0 = blockIdx.x * 128;

  f32x4 acc[4][4] = {};

  for (int k0 = 0; k0 < Kdim; k0 += 32) {
    #pragma unroll
    for (int c = 0; c < 2; ++c) {
      int chunk = c * 256 + wave * 64 + lane;
      int row = chunk >> 2;
      int hc = (chunk & 3) ^ (row & 3);   // pre-swizzled source block
      gload_lds16(A  + (size_t)(m0 + row) * Kdim + k0 + hc * 8,
                  &As[(size_t)(c * 256 + wave * 64) * 8]);
      gload_lds16(Bw + (size_t)(n0 + row) * Kdim + k0 + hc * 8,
                  &Bs[(size_t)(c * 256 + wave * 64) * 8]);
    }
    __syncthreads();
    bf16x8 af[4], bfr[4];
    #pragma unroll
    for (int m = 0; m < 4; ++m) {
      int rowl = wr * 64 + m * 16 + r;
      af[m] = *(const bf16x8*)&As[rowl * 32 + ((hi ^ (rowl & 3)) * 8)];
    }
    #pragma unroll
    for (int n = 0; n < 4; ++n) {
      int rowl = wc * 64 + n * 16 + r;
      bfr[n] = *(const bf16x8*)&Bs[rowl * 32 + ((hi ^ (rowl & 3)) * 8)];
    }
    #pragma unroll
    for (int m = 0; m < 4; ++m)
      #pragma unroll
      for (int n = 0; n < 4; ++n)
        acc[m][n] = __builtin_amdgcn_mfma_f32_16x16x32_bf16(af[m], bfr[n], acc[m][n], 0, 0, 0);
    __syncthreads();
  }

  if (OUT_MODE == 2) {
    #pragma unroll
    for (int m = 0; m < 4; ++m)
      #pragma unroll
      for (int n = 0; n < 4; ++n) {
        int row0 = m0 + wr * 64 + m * 16 + hi * 4;
        int col  = n0 + wc * 64 + n * 16 + r;
        int b = row0 >> 11, s = row0 & (Sc - 1);
        int h = col >> 6, d = col & 63;
        union { __bf16 hh[4]; uint2 u; } w;
        #pragma unroll
        for (int rg = 0; rg < 4; ++rg)
          w.hh[rg] = (__bf16)(acc[m][n][rg] + bias[col]);
        *(uint2*)&((__bf16*)outp)[(((size_t)(b * Hc + h) * HDc + d) << 11) + s] = w.u;
      }
  } else {
    #pragma unroll
    for (int m = 0; m < 4; ++m)
      #pragma unroll
      for (int n = 0; n < 4; ++n)
        #pragma unroll
        for (int rg = 0; rg < 4; ++rg) {
          int row_g = m0 + wr * 64 + m * 16 + hi * 4 + rg;
          int col_g = n0 + wc * 64 + n * 16 + r;
          float v = (acc[m][n][rg] + bias[col_g]) * scale;
          if (OUT_MODE == 0) {
            int b = row_g >> 11, s = row_g & (Sc - 1);
            int h = col_g >> 6, d = col_g & 63;
            ((__bf16*)outp)[((((size_t)b * Hc + h) * Sc + s) << 6) + d] = (__bf16)v;
          } else {
            ((float*)outp)[(size_t)row_g * Dc + col_g] = v;
          }
        }
  }
}

// ---------------- causal flash attention, LDS-free, per-wave independent ----
// Qh/Kh: [B*H][S][64] bf16 (Q pre-scaled by 1/8). Vt: [B*H][64][S] bf16.
// out: [B][S][D] bf16.
__global__ __launch_bounds__(128, 2)
void attn_causal(const __bf16* __restrict__ Qh, const __bf16* __restrict__ Kh,
                 const __bf16* __restrict__ Vt, __bf16* __restrict__ outp)
{
  const int tid = threadIdx.x;
  const int wave = tid >> 6, lane = tid & 63;
  const int r = lane & 15, hi = lane >> 4;
  const int bh = blockIdx.y;
  const int qt = wave ? (31 - (int)blockIdx.x) : (int)blockIdx.x;  // balance: i + (31-i)
  const int q0 = qt * 64;
  const __bf16* Q = Qh + (size_t)bh * (Sc * HDc);
  const __bf16* K = Kh + (size_t)bh * (Sc * HDc);
  const __bf16* V = Vt + (size_t)bh * (HDc * Sc);

  // Q fragments (B-operand: col=r, k=hi*8+j per 32-chunk)
  bf16x8 qf[4][2];
  #pragma unroll
  for (int m = 0; m < 4; ++m)
    #pragma unroll
    for (int kc = 0; kc < 2; ++kc)
      qf[m][kc] = *(const bf16x8*)&Q[(size_t)(q0 + m * 16 + r) * 64 + kc * 32 + hi * 8];

  f32x4 o_acc[4][4] = {};   // O^T: row hd = n*16+hi*4+rg, col q = m*16+r
  float mrow[4], lrow[4];
  #pragma unroll
  for (int m = 0; m < 4; ++m) { mrow[m] = -1e30f; lrow[m] = 0.f; }

  const int T = qt + 1;
  bf16x8 kf[4][2], vf[4][2], pb[4][2];

  // preload tile 0
  #pragma unroll
  for (int n = 0; n < 4; ++n)
    #pragma unroll
    for (int kc = 0; kc < 2; ++kc) {
      kf[n][kc] = *(const bf16x8*)&K[(size_t)(n * 16 + r) * 64 + kc * 32 + hi * 8];
      vf[n][kc] = *(const bf16x8*)&V[(size_t)(n * 16 + r) * Sc + kc * 32 + hi * 8];
    }

  for (int t = 0; t < T; ++t) {
    const bool diag = (t == T - 1);
    const int kvn = (t + 1) * 64;

    // ---- phase 1: QK^T (swapped) + softmax + in-register P exchange ----
    #pragma unroll
    for (int m = 0; m < 4; ++m) {
      f32x4 sn[4];
      #pragma unroll
      for (int n = 0; n < 4; ++n) {
        f32x4 z = {0.f, 0.f, 0.f, 0.f};
        sn[n] = __builtin_amdgcn_mfma_f32_16x16x32_bf16(kf[n][0], qf[m][0], z, 0, 0, 0);
        sn[n] = __builtin_amdgcn_mfma_f32_16x16x32_bf16(kf[n][1], qf[m][1], sn[n], 0, 0, 0);
      }
      if (diag) {
        #pragma unroll
        for (int n = 0; n < 4; ++n)
          #pragma unroll
          for (int rg = 0; rg < 4; ++rg)
            if (n * 16 + hi * 4 + rg > m * 16 + r) sn[n][rg] = -1e30f;
      }
      float mx = fmaxf(fmaxf(fmaxf(sn[0][0], sn[0][1]), fmaxf(sn[0][2], sn[0][3])),
                       fmaxf(fmaxf(sn[1][0], sn[1][1]), fmaxf(sn[1][2], sn[1][3])));
      mx = fmaxf(mx, fmaxf(fmaxf(fmaxf(sn[2][0], sn[2][1]), fmaxf(sn[2][2], sn[2][3])),
                           fmaxf(fmaxf(sn[3][0], sn[3][1]), fmaxf(sn[3][2], sn[3][3]))));
      mx = fmaxf(mx, __shfl_xor(mx, 16));
      mx = fmaxf(mx, __shfl_xor(mx, 32));
      float mnew = fmaxf(mrow[m], mx);
      float sc = __expf(mrow[m] - mnew);
      mrow[m] = mnew;
      float rs = 0.f;
      #pragma unroll
      for (int n = 0; n < 4; ++n)
        #pragma unroll
        for (int rg = 0; rg < 4; ++rg) {
          float p = __expf(sn[n][rg] - mnew);
          sn[n][rg] = p;
          rs += p;
        }
      rs += __shfl_xor(rs, 16);
      rs += __shfl_xor(rs, 32);
      lrow[m] = lrow[m] * sc + rs;
      #pragma unroll
      for (int n = 0; n < 4; ++n) o_acc[m][n] *= sc;

      // exchange P^T fragments -> B-operand layout.
      // After permlane32_swap: p0a@(r,hi) = P_{hi>>1}_a from hi'=(hi&1);
      //                        p1a@(r,hi) = P_{hi>>1}_a from hi'=2+(hi&1).
      // Target: u[0]/u[1] need hi'=2(hi&1); u[2]/u[3] need hi'=2(hi&1)+1.
      //   => u[0] = (hi&1) ? xor16(p1a) : p0a
      //      u[2] = (hi&1) ? p1a        : xor16(p0a)
      #pragma unroll
      for (int kc = 0; kc < 2; ++kc) {
        uint32_t p0a, p0b, p1a, p1b;
        asm("v_cvt_pk_bf16_f32 %0, %1, %2" : "=v"(p0a) : "v"(sn[2*kc][0]),   "v"(sn[2*kc][1]));
        asm("v_cvt_pk_bf16_f32 %0, %1, %2" : "=v"(p0b) : "v"(sn[2*kc][2]),   "v"(sn[2*kc][3]));
        asm("v_cvt_pk_bf16_f32 %0, %1, %2" : "=v"(p1a) : "v"(sn[2*kc+1][0]), "v"(sn[2*kc+1][1]));
        asm("v_cvt_pk_bf16_f32 %0, %1, %2" : "=v"(p1b) : "v"(sn[2*kc+1][2]), "v"(sn[2*kc+1][3]));
        // swap: p0x = {P0 lanes0-31 | P1 lanes0-31}, p1x = {P0 lanes32-63 | P1 lanes32-63}
        asm("v_permlane32_swap_b32 %0, %1" : "+v"(p0a), "+v"(p1a));
        asm("v_permlane32_swap_b32 %0, %1" : "+v"(p0b), "+v"(p1b));
        uint32_t Xa = (uint32_t)__shfl_xor((int)p1a, 16);
        uint32_t Xb = (uint32_t)__shfl_xor((int)p1b, 16);
        uint32_t Ya = (uint32_t)__shfl_xor((int)p0a, 16);
        uint32_t Yb = (uint32_t)__shfl_xor((int)p0b, 16);
        union { uint32_t u[4]; bf16x8 v; } pk;
        pk.u[0] = (hi & 1) ? Xa : p0a;
        pk.u[1] = (hi & 1) ? Xb : p0b;
        pk.u[2] = (hi & 1) ? p1a : Ya;
        pk.u[3] = (hi & 1) ? p1b : Yb;
        pb[m][kc] = pk.v;
      }
    }

    // prefetch next K tile (kf dead after phase 1)
    if (t + 1 < T) {
      #pragma unroll
      for (int n = 0; n < 4; ++n)
        #pragma unroll
        for (int kc = 0; kc < 2; ++kc)
          kf[n][kc] = *(const bf16x8*)&K[(size_t)(kvn + n * 16 + r) * 64 + kc * 32 + hi * 8];
    }

    // ---- phase 2: PV (swapped: O^T += V^T-frag * P-frag) ----
    #pragma unroll
    for (int m = 0; m < 4; ++m)
      #pragma unroll
      for (int n = 0; n < 4; ++n) {
        o_acc[m][n] = __builtin_amdgcn_mfma_f32_16x16x32_bf16(vf[n][0], pb[m][0], o_acc[m][n], 0, 0, 0);
        o_acc[m][n] = __builtin_amdgcn_mfma_f32_16x16x32_bf16(vf[n][1], pb[m][1], o_acc[m][n], 0, 0, 0);
      }

    // prefetch next V tile (vf dead after phase 2)
    if (t + 1 < T) {
      #pragma unroll
      for (int n = 0; n < 4; ++n)
        #pragma unroll
        for (int kc = 0; kc < 2; ++kc)
          vf[n][kc] = *(const bf16x8*)&V[(size_t)(n * 16 + r) * Sc + kvn + kc * 32 + hi * 8];
    }
  }

  // epilogue: out[b][q][h*64+hd], pack 4 consecutive hd (rg) per store
  const int b = bh >> 4, h = bh & 15;
  #pragma unroll
  for (int m = 0; m < 4; ++m) {
    float inv = 1.f / lrow[m];
    size_t row = (size_t)b * Sc + q0 + m * 16 + r;
    #pragma unroll
    for (int n = 0; n < 4; ++n) {
      union { __bf16 hh[4]; uint2 u; } w;
      #pragma unroll
      for (int rg = 0; rg < 4; ++rg)
        w.hh[rg] = (__bf16)(o_acc[m][n][rg] * inv);
      int col = h * 64 + n * 16 + hi * 4;
      *(uint2*)&outp[row * Dc + col] = w.u;
    }
  }
}

// ---------------- launch ----------------
extern "C" void kernel_launch(void* const* d_in, const int* in_sizes, int n_in,
                              void* d_out, int out_size, void* d_ws, size_t ws_size,
                              hipStream_t stream) {
  const float* q  = (const float*)d_in[0];
  const float* k  = (const float*)d_in[1];
  const float* v  = (const float*)d_in[2];
  const float* Wq = (const float*)d_in[4];
  const float* bq = (const float*)d_in[5];
  const float* Wk = (const float*)d_in[6];
  const float* bk = (const float*)d_in[7];
  const float* Wv = (const float*)d_in[8];
  const float* bv = (const float*)d_in[9];
  const float* Wo = (const float*)d_in[10];
  const float* bo = (const float*)d_in[11];

  char* ws = (char*)d_ws;
  constexpr size_t MB = 1u << 20;
  __bf16* Wqb = (__bf16*)(ws + 0 * MB);
  __bf16* Wkb = (__bf16*)(ws + 2 * MB);
  __bf16* Wvb = (__bf16*)(ws + 4 * MB);
  __bf16* Wob = (__bf16*)(ws + 6 * MB);
  __bf16* Xbf = (__bf16*)(ws + 8 * MB);    // 16 MB: X (reused), then attn out
  __bf16* QhB = (__bf16*)(ws + 24 * MB);
  __bf16* KhB = (__bf16*)(ws + 40 * MB);
  __bf16* VtB = (__bf16*)(ws + 56 * MB);   // V^T: [B*H][64][S]

  const int nW4 = (Dc * Dc) / 4;           // 262144
  const int nX4 = (Mrows * Dc) / 4;        // 2097152
  cvt_f32_to_bf16<<<(nW4 + 255) / 256, 256, 0, stream>>>(Wq, Wqb, nW4);
  cvt_f32_to_bf16<<<(nW4 + 255) / 256, 256, 0, stream>>>(Wk, Wkb, nW4);
  cvt_f32_to_bf16<<<(nW4 + 255) / 256, 256, 0, stream>>>(Wv, Wvb, nW4);
  cvt_f32_to_bf16<<<(nW4 + 255) / 256, 256, 0, stream>>>(Wo, Wob, nW4);

  dim3 gg(Ndim / 128, Mrows / 128);  // (8, 64)
  cvt_f32_to_bf16<<<(nX4 + 255) / 256, 256, 0, stream>>>(q, Xbf, nX4);
  gemm_bt<0><<<gg, 256, 0, stream>>>(Xbf, Wqb, bq, QhB, 0.125f);
  cvt_f32_to_bf16<<<(nX4 + 255) / 256, 256, 0, stream>>>(k, Xbf, nX4);
  gemm_bt<0><<<gg, 256, 0, stream>>>(Xbf, Wkb, bk, KhB, 1.0f);
  cvt_f32_to_bf16<<<(nX4 + 255) / 256, 256, 0, stream>>>(v, Xbf, nX4);
  gemm_bt<2><<<gg, 256, 0, stream>>>(Xbf, Wvb, bv, VtB, 1.0f);

  attn_causal<<<dim3(16, Bc * Hc), 128, 0, stream>>>(QhB, KhB, VtB, Xbf);

  gemm_bt<1><<<gg, 256, 0, stream>>>(Xbf, Wob, bo, d_out, 1.0f);
}